// Round 8
// baseline (486.911 us; speedup 1.0000x reference)
//
#include <hip/hip_runtime.h>
#include <cstdint>
#include <cstddef>

typedef _Float16 HT;
typedef _Float16 h8 __attribute__((ext_vector_type(8)));
typedef _Float16 h4 __attribute__((ext_vector_type(4)));
typedef float f32x4 __attribute__((ext_vector_type(4)));
typedef float f32x16 __attribute__((ext_vector_type(16)));

constexpr int Tn  = 2048;
constexpr int Dm  = 2048;
constexpr int Hh  = 16;
constexpr int RDc = 64;
constexpr int QRc = 1536;
constexpr int KVRc= 512;
constexpr int BT  = 4096;

#define VWAIT(N) asm volatile("s_waitcnt vmcnt(" #N ")" ::: "memory")
#define SBAR()   __builtin_amdgcn_s_barrier()

__device__ __forceinline__ f32x4 mfma16(h8 a, h8 b, f32x4 c) {
    return __builtin_amdgcn_mfma_f32_16x16x32_f16(a, b, c, 0, 0, 0);
}
__device__ __forceinline__ f32x16 mfma32(h8 a, h8 b, f32x16 c) {
    return __builtin_amdgcn_mfma_f32_32x32x16_f16(a, b, c, 0, 0, 0);
}
__device__ __forceinline__ void gload_lds16(const void* g, void* l) {
    __builtin_amdgcn_global_load_lds(
        (const __attribute__((address_space(1))) unsigned int*)g,
        (__attribute__((address_space(3))) unsigned int*)l, 16, 0, 0);
}
__device__ __forceinline__ unsigned pkf16(float a, float b) {
    union { _Float16 h[2]; unsigned u; } t;
    t.h[0] = (_Float16)a; t.h[1] = (_Float16)b;
    return t.u;
}

// ---------------------------------------------------------------------------
// cos/sin table: cstab[t*32+i] = (cos, sin) of t * 10000^(-i/32)
// ---------------------------------------------------------------------------
__global__ __launch_bounds__(256)
void cstab_kernel(float2* __restrict__ cs)
{
    const int idx = blockIdx.x * 256 + threadIdx.x;   // 65536
    const int t = idx >> 5, i = idx & 31;
    const float ang = (float)t * exp2f(-(float)i * (13.287712379549449f / 32.f));
    cs[idx] = make_float2(cosf(ang), sinf(ang));
}

// ---------------------------------------------------------------------------
// Merged weight transpose+convert: 8 segments, src fp32 [K][N] -> dst [N][K]
// ---------------------------------------------------------------------------
struct WT8 {
    const float* s[8];
    HT* d[8];
    int K[8], N[8], start[8];
};

__global__ __launch_bounds__(256)
void wtrans8_kernel(WT8 p)
{
    __shared__ float Ts[64][65];
    int seg = 0;
    #pragma unroll
    for (int i = 1; i < 8; i++) if ((int)blockIdx.x >= p.start[i]) seg = i;
    const float* src = p.s[seg];
    HT* dst = p.d[seg];
    const int K = p.K[seg], N = p.N[seg];
    const int bx = blockIdx.x - p.start[seg];
    const int nx = N >> 6;
    const int n0 = (bx % nx) * 64, k0 = (bx / nx) * 64;
    const int tid = threadIdx.x;
    {
        const int r = tid >> 2, c0 = (tid & 3) * 16;
        const float* s = src + (size_t)(k0 + r) * N + n0 + c0;
        #pragma unroll
        for (int j = 0; j < 4; j++)
            *reinterpret_cast<f32x4*>(&Ts[r][c0 + j * 4]) = *reinterpret_cast<const f32x4*>(s + j * 4);
    }
    __syncthreads();
    {
        const int c = tid >> 2, kq = (tid & 3) * 16;
        h8 o0, o1;
        #pragma unroll
        for (int j = 0; j < 8; j++) { o0[j] = (HT)Ts[kq + j][c]; o1[j] = (HT)Ts[kq + 8 + j][c]; }
        HT* d = dst + (size_t)(n0 + c) * K + k0 + kq;
        *reinterpret_cast<h8*>(d)     = o0;
        *reinterpret_cast<h8*>(d + 8) = o1;
    }
}

// ---------------------------------------------------------------------------
__global__ __launch_bounds__(256)
void convx_kernel(const float* __restrict__ x, HT* __restrict__ x16)
{
    const size_t i = ((size_t)blockIdx.x * 256 + threadIdx.x) * 8;
    f32x4 a = *reinterpret_cast<const f32x4*>(x + i);
    f32x4 b = *reinterpret_cast<const f32x4*>(x + i + 4);
    h8 v;
    #pragma unroll
    for (int j = 0; j < 4; j++) { v[j] = (HT)a[j]; v[4 + j] = (HT)b[j]; }
    *reinterpret_cast<h8*>(x16 + i) = v;
}

// ---------------------------------------------------------------------------
// Double-buffered m97-style GEMM, 128x128 tile, BK=32, counted vmcnt,
// 2-bit XOR LDS swizzle both-sides. EPI: 0=latent(cq|ckv|kr16-rope)
// 1=Q(qn|qr-rope) 2=KV(kn+out_k | vt+out_v) 3=OUT(fp32)
// ---------------------------------------------------------------------------
template<int EPI>
__global__ __launch_bounds__(256)
void gemm16d(const HT* __restrict__ A, const HT* __restrict__ Bt, const int K,
             HT* __restrict__ o1, HT* __restrict__ o2, HT* __restrict__ o3,
             float* __restrict__ f1, float* __restrict__ f2,
             const float2* __restrict__ cstab)
{
    __shared__ HT As[2][4096];
    __shared__ HT Bs[2][4096];

    const int tid  = threadIdx.x;
    const int lane = tid & 63;
    const int l15  = lane & 15, l4 = lane >> 4;
    const int w    = tid >> 6;
    const int wr   = w >> 1, wc = w & 1;
    const int m0   = blockIdx.y * 128;
    const int n0   = blockIdx.x * 128;

    f32x4 acc[4][4] = {};
    const int nk = K >> 5;

    const int schunk = ((lane & 3) ^ ((lane >> 2) & 3) ^ ((lane >> 4) & 3)) * 8;

#define GSTAGE(as_, bs_, kt_) do {                                             \
    _Pragma("unroll")                                                          \
    for (int i_ = 0; i_ < 2; i_++) {                                           \
        const int row_ = (w * 2 + i_) * 16 + (lane >> 2);                      \
        gload_lds16(A  + (size_t)(m0 + row_) * K + (kt_) + schunk,             \
                    (as_) + (w * 2 + i_) * 512);                               \
        gload_lds16(Bt + (size_t)(n0 + row_) * K + (kt_) + schunk,             \
                    (bs_) + (w * 2 + i_) * 512);                               \
    } } while (0)

    GSTAGE(As[0], Bs[0], 0);

    const int sl = (l4 ^ (l15 & 3) ^ ((l15 >> 2) & 3)) * 8;

    for (int kt = 0; kt < nk; kt++) {
        HT* as = As[kt & 1];
        HT* bs = Bs[kt & 1];
        if (kt + 1 < nk) {
            GSTAGE(As[(kt + 1) & 1], Bs[(kt + 1) & 1], (kt + 1) * 32);
            VWAIT(4);
        } else {
            VWAIT(0);
        }
        SBAR();

        h8 af[4], bf[4];
        #pragma unroll
        for (int f = 0; f < 4; f++)
            af[f] = *reinterpret_cast<const h8*>(&as[(wr * 64 + f * 16 + l15) * 32 + sl]);
        #pragma unroll
        for (int g = 0; g < 4; g++)
            bf[g] = *reinterpret_cast<const h8*>(&bs[(wc * 64 + g * 16 + l15) * 32 + sl]);
        #pragma unroll
        for (int f = 0; f < 4; f++)
            #pragma unroll
            for (int g = 0; g < 4; g++)
                acc[f][g] = mfma16(af[f], bf[g], acc[f][g]);
        SBAR();
    }
#undef GSTAGE

    #pragma unroll
    for (int f = 0; f < 4; f++) {
        #pragma unroll
        for (int g = 0; g < 4; g++) {
            const int row = m0 + wr * 64 + f * 16 + l4 * 4;
            const int col = n0 + wc * 64 + g * 16 + l15;
            if constexpr (EPI == 3) {
                #pragma unroll
                for (int r = 0; r < 4; r++)
                    f1[(size_t)(row + r) * 2048 + col] = acc[f][g][r];
            } else if constexpr (EPI == 0) {
                if (col < 1536) {
                    #pragma unroll
                    for (int r = 0; r < 4; r++)
                        o1[(size_t)(row + r) * 1536 + col] = (HT)acc[f][g][r];
                } else if (col < 2048) {
                    #pragma unroll
                    for (int r = 0; r < 4; r++)
                        o2[(size_t)(row + r) * 512 + (col - 1536)] = (HT)acc[f][g][r];
                } else if (col < 2112) {
                    const int cc = col - 2048;
                    const int i = cc >> 1;
                    const bool odd = cc & 1;
                    #pragma unroll
                    for (int r = 0; r < 4; r++) {
                        const int t = (row + r) & (Tn - 1);
                        const float2 cs = cstab[t * 32 + i];
                        const float v = acc[f][g][r];
                        const float p = __shfl_xor(v, 1);
                        const float ov = odd ? p * cs.y + v * cs.x : v * cs.x - p * cs.y;
                        o3[(size_t)(row + r) * 64 + cc] = (HT)ov;
                    }
                }
            } else if constexpr (EPI == 1) {
                if (col < 2048) {
                    #pragma unroll
                    for (int r = 0; r < 4; r++)
                        o1[(size_t)(row + r) * 2048 + col] = (HT)acc[f][g][r];
                } else {
                    const int cc = col - 2048;
                    const int i = (cc & 63) >> 1;
                    const bool odd = cc & 1;
                    #pragma unroll
                    for (int r = 0; r < 4; r++) {
                        const int t = (row + r) & (Tn - 1);
                        const float2 cs = cstab[t * 32 + i];
                        const float v = acc[f][g][r];
                        const float p = __shfl_xor(v, 1);
                        const float ov = odd ? p * cs.y + v * cs.x : v * cs.x - p * cs.y;
                        o2[(size_t)(row + r) * 1024 + cc] = (HT)ov;
                    }
                }
            } else {  // EPI == 2
                if (col < 2048) {
                    const int h = col >> 7, d = col & 127;
                    #pragma unroll
                    for (int r = 0; r < 4; r++) {
                        const int rw = row + r;
                        const int b = rw >> 11, t = rw & (Tn - 1);
                        o1[(size_t)rw * 2048 + col] = (HT)acc[f][g][r];
                        f1[((size_t)(b * Hh + h) * Tn + t) * 192 + d] = acc[f][g][r];
                    }
                } else {
                    const int c2 = col - 2048;
                    const int h = c2 >> 7, d = c2 & 127;
                    const int b = row >> 11, t0 = row & (Tn - 1);
                    h4 pk;
                    #pragma unroll
                    for (int r = 0; r < 4; r++) {
                        f2[((size_t)(b * Hh + h) * Tn + t0 + r) * 128 + d] = acc[f][g][r];
                        pk[r] = (HT)acc[f][g][r];
                    }
                    *reinterpret_cast<h4*>(&o3[((size_t)(b * Hh + h) * 128 + d) * Tn + t0]) = pk;
                }
            }
        }
    }
}

// ---------------------------------------------------------------------------
// broadcast rope slice of out_k across 16 heads (fp32)
// ---------------------------------------------------------------------------
__global__ __launch_bounds__(256)
void kropebc_kernel(const HT* __restrict__ kr16, float* __restrict__ out_k)
{
    const int idx = blockIdx.x * 256 + threadIdx.x;    // 2*2048*16
    const int j4 = (idx & 15) * 4;
    const int t  = (idx >> 4) & (Tn - 1);
    const int b  = idx >> 15;
    h4 v = *reinterpret_cast<const h4*>(&kr16[((size_t)(b * Tn + t)) * 64 + j4]);
    f32x4 f;
    #pragma unroll
    for (int r = 0; r < 4; r++) f[r] = (float)v[r];
    #pragma unroll
    for (int h = 0; h < Hh; h++)
        *reinterpret_cast<f32x4*>(&out_k[((size_t)(b * Hh + h) * Tn + t) * 192 + 128 + j4]) = f;
}

// ---------------------------------------------------------------------------
// merged RMSNorm: grid (4096, 2); y=0 -> (Xa, ga, 1536), y=1 -> (Xb, gb, 512)
// ---------------------------------------------------------------------------
__global__ __launch_bounds__(256)
void rmsnorm2_kernel(HT* __restrict__ Xa, const float* __restrict__ ga,
                     HT* __restrict__ Xb, const float* __restrict__ gb)
{
    const int which = blockIdx.y;
    HT* X = which ? Xb : Xa;
    const float* g = which ? gb : ga;
    const int N = which ? 512 : 1536;
    const int row = blockIdx.x;
    HT* x = X + (size_t)row * N;
    float ss = 0.f;
    for (int i = threadIdx.x * 8; i < N; i += 2048) {
        h8 v = *reinterpret_cast<const h8*>(&x[i]);
        #pragma unroll
        for (int j = 0; j < 8; j++) { float f = (float)v[j]; ss += f * f; }
    }
    #pragma unroll
    for (int sh = 32; sh >= 1; sh >>= 1) ss += __shfl_xor(ss, sh);
    __shared__ float red[4];
    if ((threadIdx.x & 63) == 0) red[threadIdx.x >> 6] = ss;
    __syncthreads();
    const float tot = red[0] + red[1] + red[2] + red[3];
    const float scale = rsqrtf(tot / (float)N + 1e-6f);
    for (int i = threadIdx.x * 8; i < N; i += 2048) {
        h8 v = *reinterpret_cast<const h8*>(&x[i]);
        f32x4 g0 = *reinterpret_cast<const f32x4*>(&g[i]);
        f32x4 g1 = *reinterpret_cast<const f32x4*>(&g[i + 4]);
        #pragma unroll
        for (int j = 0; j < 4; j++) { v[j]   = (HT)((float)v[j]   * scale * g0[j]);
                                      v[4+j] = (HT)((float)v[4+j] * scale * g1[j]); }
        *reinterpret_cast<h8*>(&x[i]) = v;
    }
}

// ---------------------------------------------------------------------------
// Flash attention v8: swapped-QK 32x32 MFMA, in-register softmax.
// Wave = 32 q-rows. Block = 4 waves covering mirrored 64-row tiles j, 31-j.
// S^T = mfma32(A=K-frag, B=Q-frag): lane owns q = lane&31, holds 16 of 32 k
// (k_local = (r&3)+8*(r>>2)+4*hi, hi = lane>>5; partner lane^32 has rest).
// Softmax per-lane + one shfl_xor(32). P packed to fp16 + lane-swap -> PV
// A-frags. exp2 domain (scale folded into Q), defer-max THR=8.
// ---------------------------------------------------------------------------
__global__ __launch_bounds__(256)
void attn8_kernel(const HT* __restrict__ qn, const HT* __restrict__ qr,
                  const HT* __restrict__ kn, const HT* __restrict__ kr16,
                  const HT* __restrict__ vt, HT* __restrict__ ao)
{
    __shared__ HT Ks[64 * 128];    // [krow][16 chunks], chunk ^= (row&15)
    __shared__ HT Vs[128 * 64];    // [d][8 chunks],     chunk ^= (d&7)

    const int tid  = threadIdx.x;
    const int lane = tid & 63;
    const int l31  = lane & 31;
    const int hi   = lane >> 5;
    const int w    = tid >> 6;

    const int bid = blockIdx.x;                   // 512
    const int wid = (bid & 7) * 64 + (bid >> 3);  // XCD-chunked: 4 (h,b)/XCD
    const int j   = wid & 15;
    const int hb  = wid >> 4;
    const int h   = hb >> 1;
    const int b   = hb & 1;

    const size_t bT = (size_t)b * Tn;
    const HT* vt_h = vt + ((size_t)(b * Hh + h) * 128) * Tn;
    const HT* krb  = kr16 + bT * 64;

    const int mytile = (w < 2) ? j : (31 - j);
    const int qw   = mytile * 64 + (w & 1) * 32;
    const int qabs = qw + l31;

    // hoist Q as B-frags (col = q = lane&31, kd = step*16 + hi*8), exp2-scaled
    h8 bq[12];
    {
        const HT sc = (HT)(0.07216878364870323f * 1.4426950408889634f);
        const HT* pn = qn + (bT + qabs) * 2048 + h * 128 + hi * 8;
        #pragma unroll
        for (int s = 0; s < 8; s++) bq[s] = *reinterpret_cast<const h8*>(pn + s * 16) * sc;
        const HT* pr = qr + (bT + qabs) * 1024 + h * 64 + hi * 8;
        #pragma unroll
        for (int s = 0; s < 4; s++) bq[8 + s] = *reinterpret_cast<const h8*>(pr + s * 16) * sc;
    }

    f32x16 O[4] = {};
    float m_i = -1e30f, l_i = 0.f;

    const int nkb = 32 - j;
    for (int kb64 = 0; kb64 < nkb; kb64++) {
        const int kb = kb64 * 64;
        __syncthreads();
        // ---- cooperative stage (8 x 1KB chunks per wave) ----
        #pragma unroll
        for (int c = 0; c < 4; c++) {             // K nope 16KB
            const int r  = (w * 4 + c) * 4 + (lane >> 4);
            const int cl = (lane & 15) ^ (r & 15);
            gload_lds16(kn + (bT + kb + r) * 2048 + h * 128 + cl * 8,
                        &Ks[(w * 4 + c) * 512]);
        }
        #pragma unroll
        for (int c = 0; c < 4; c++) {             // V^T 16KB
            const int d  = (w * 4 + c) * 8 + (lane >> 3);
            const int cl = (lane & 7) ^ (d & 7);
            gload_lds16(vt_h + (size_t)d * Tn + kb + cl * 8,
                        &Vs[(w * 4 + c) * 512]);
        }
        __syncthreads();

        if (kb <= qw + 31) {
            #pragma unroll
            for (int grp = 0; grp < 2; grp++) {
                const int krow = grp * 32 + l31;
                // ---- S^T = K * Q^T (two accumulator chains for ILP) ----
                f32x16 sA = {}, sB = {};
                __builtin_amdgcn_s_setprio(1);
                #pragma unroll
                for (int st = 0; st < 4; st++) {
                    const int chA = (st * 2 + hi) ^ (krow & 15);
                    const int chB = ((st + 4) * 2 + hi) ^ (krow & 15);
                    sA = mfma32(*reinterpret_cast<const h8*>(&Ks[krow * 128 + chA * 8]), bq[st], sA);
                    sB = mfma32(*reinterpret_cast<const h8*>(&Ks[krow * 128 + chB * 8]), bq[st + 4], sB);
                }
                {
                    const HT* rp = krb + (size_t)(kb + krow) * 64 + hi * 8;
                    sA = mfma32(*reinterpret_cast<const h8*>(rp),      bq[8],  sA);
                    sB = mfma32(*reinterpret_cast<const h8*>(rp + 16), bq[9],  sB);
                    sA = mfma32(*reinterpret_cast<const h8*>(rp + 32), bq[10], sA);
                    sB = mfma32(*reinterpret_cast<const h8*>(rp + 48), bq[11], sB);
                }
                __builtin_amdgcn_s_setprio(0);

                // ---- per-lane masked softmax (exp2 domain) ----
                float p[16];
                float mx = -1e30f;
                #pragma unroll
                for (int r = 0; r < 16; r++) {
                    const int kl  = (r & 3) + 8 * (r >> 2) + 4 * hi;
                    const int kab = kb + grp * 32 + kl;
                    const float sv = sA[r] + sB[r];
                    p[r] = (kab <= qabs) ? sv : -1e30f;
                    mx = fmaxf(mx, p[r]);
                }
                mx = fmaxf(mx, __shfl_xor(mx, 32));
                if (!__all(mx <= m_i + 8.f)) {
                    const float mn = fmaxf(m_i, mx);
                    const float alpha = __builtin_exp2f(m_i - mn);
                    m_i = mn;
                    l_i *= alpha;
                    float av[16];
                    #pragma unroll
                    for (int r = 0; r < 16; r++) {
                        const int ql = (r & 3) + 8 * (r >> 2) + 4 * hi;
                        av[r] = __shfl(alpha, ql);
                    }
                    #pragma unroll
                    for (int db = 0; db < 4; db++)
                        #pragma unroll
                        for (int r = 0; r < 16; r++) O[db][r] *= av[r];
                }
                float rs = 0.f;
                #pragma unroll
                for (int r = 0; r < 16; r++) {
                    p[r] = __builtin_exp2f(p[r] - m_i);
                    rs += p[r];
                }
                l_i += rs + __shfl_xor(rs, 32);

                // ---- pack P to fp16, swap halves across lane^32 ----
                unsigned u[8], sw[8];
                #pragma unroll
                for (int bb = 0; bb < 4; bb++) {
                    u[2 * bb]     = pkf16(p[4 * bb],     p[4 * bb + 1]);
                    u[2 * bb + 1] = pkf16(p[4 * bb + 2], p[4 * bb + 3]);
                }
                #pragma unroll
                for (int i = 0; i < 8; i++) sw[i] = (unsigned)__shfl_xor((int)u[i], 32);

                // ---- O += P @ V (A = P-frag per 16-k step, B = V^T frag) ----
                __builtin_amdgcn_s_setprio(1);
                #pragma unroll
                for (int t = 0; t < 2; t++) {
                    const int bb = 2 * t + hi;
                    union { unsigned uu[4]; h8 v; } pa;
                    pa.uu[0] = hi ? sw[2 * bb]     : u[2 * bb];
                    pa.uu[1] = hi ? sw[2 * bb + 1] : u[2 * bb + 1];
                    pa.uu[2] = hi ? u[2 * bb]      : sw[2 * bb];
                    pa.uu[3] = hi ? u[2 * bb + 1]  : sw[2 * bb + 1];
                    const int ch = grp * 4 + 2 * t + hi;
                    #pragma unroll
                    for (int db = 0; db < 4; db++) {
                        const int d = db * 32 + l31;
                        const h8 vf = *reinterpret_cast<const h8*>(&Vs[d * 64 + ((ch ^ (d & 7)) * 8)]);
                        O[db] = mfma32(pa.v, vf, O[db]);
                    }
                }
                __builtin_amdgcn_s_setprio(0);
            }
        }
    }

    // ---- normalize (redistribute 1/l to C-row lanes) + store ----
    float iv[16];
    {
        const float inv = 1.0f / l_i;
        #pragma unroll
        for (int r = 0; r < 16; r++) {
            const int ql = (r & 3) + 8 * (r >> 2) + 4 * hi;
            iv[r] = __shfl(inv, ql);
        }
    }
    #pragma unroll
    for (int db = 0; db < 4; db++) {
        #pragma unroll
        for (int r = 0; r < 16; r++) {
            const int ql = (r & 3) + 8 * (r >> 2) + 4 * hi;
            ao[(bT + qw + ql) * 2048 + h * 128 + db * 32 + l31] = (HT)(O[db][r] * iv[r]);
        }
    }
}

// ---------------------------------------------------------------------------
extern "C" void kernel_launch(void* const* d_in, const int* in_sizes, int n_in,
                              void* d_out, int out_size, void* d_ws, size_t ws_size,
                              hipStream_t stream)
{
    const float* x     = (const float*)d_in[0];
    const float* w_cq  = (const float*)d_in[1];
    const float* g_q   = (const float*)d_in[2];
    const float* w_ckv = (const float*)d_in[3];
    const float* g_kv  = (const float*)d_in[4];
    const float* w_dqn = (const float*)d_in[5];
    const float* w_dqr = (const float*)d_in[6];
    const float* w_dkn = (const float*)d_in[7];
    const float* w_dv  = (const float*)d_in[8];
    const float* w_kr  = (const float*)d_in[9];
    const float* w_out = (const float*)d_in[10];

    char* ws = (char*)d_ws;
    // weight region (dead after their GEMM -> vt aliases it)
    HT* cqT   = (HT*)(ws + 0);           // [1536][2048]  6,291,456
    HT* ckvT  = (HT*)(ws + 6291456);     // [512][2048]   2,097,152
    HT* krT   = (HT*)(ws + 8388608);     // [64][2048]      262,144
    //  pad region [8650752, 8912896) read as garbage B rows (never written out)
    HT* dqnT  = (HT*)(ws + 8912896);     // [2048][1536]  6,291,456
    HT* dqrT  = (HT*)(ws + 15204352);    // [1024][1536]  3,145,728
    HT* dknT  = (HT*)(ws + 18350080);    // [2048][512]   2,097,152
    HT* dvT   = (HT*)(ws + 20447232);    // [2048][512]   2,097,152
    HT* outT  = (HT*)(ws + 22544384);    // [2048][2048]  8,388,608
    HT* cq    = (HT*)(ws + 30932992);    // [4096][1536] 12,582,912
    HT* ckv   = (HT*)(ws + 43515904);    // [4096][512]   4,194,304
    HT* qn    = (HT*)(ws + 47710208);    // [4096][2048] 16,777,216 (x16/ao alias)
    HT* qr    = (HT*)(ws + 64487424);    // [4096][1024]  8,388,608
    HT* kn    = (HT*)(ws + 72876032);    // [4096][2048] 16,777,216
    HT* kr16  = (HT*)(ws + 89653248);    // [4096][64]      524,288  (end 90,177,536)
    HT* vt    = (HT*)(ws + 0);           // [2][16][128][2048] 16,777,216 (alias)
    HT* x16   = qn;                      // x16 dead before qn written
    HT* ao    = qn;                      // attn reads/writes same (row,h) slice

    float* out_o = (float*)d_out;
    float* out_k = out_o + (size_t)BT * Dm;
    float* out_v = out_k + (size_t)2 * Hh * Tn * 192;
    float2* cstab = (float2*)out_v;      // stashed in out_v head; KV GEMM
                                         // overwrites it AFTER last use (Q GEMM)

    const dim3 blk(256);

    cstab_kernel<<<dim3(256), blk, 0, stream>>>(cstab);

    // merged weight transposes: src [K][N] -> dst [N][K]
    WT8 wt;
    wt.s[0]=w_cq;  wt.d[0]=cqT;  wt.K[0]=2048; wt.N[0]=1536;
    wt.s[1]=w_ckv; wt.d[1]=ckvT; wt.K[1]=2048; wt.N[1]=512;
    wt.s[2]=w_kr;  wt.d[2]=krT;  wt.K[2]=2048; wt.N[2]=64;
    wt.s[3]=w_dqn; wt.d[3]=dqnT; wt.K[3]=1536; wt.N[3]=2048;
    wt.s[4]=w_dqr; wt.d[4]=dqrT; wt.K[4]=1536; wt.N[4]=1024;
    wt.s[5]=w_dkn; wt.d[5]=dknT; wt.K[5]=512;  wt.N[5]=2048;
    wt.s[6]=w_dv;  wt.d[6]=dvT;  wt.K[6]=512;  wt.N[6]=2048;
    wt.s[7]=w_out; wt.d[7]=outT; wt.K[7]=2048; wt.N[7]=2048;
    {
        int acc = 0;
        for (int i = 0; i < 8; i++) {
            wt.start[i] = acc;
            acc += (wt.N[i] >> 6) * (wt.K[i] >> 6);
        }
        wtrans8_kernel<<<dim3(acc), blk, 0, stream>>>(wt);   // acc = 3744
    }

    convx_kernel<<<dim3(4096), blk, 0, stream>>>(x, x16);

    // fused latent GEMM: N=2176 (cq | ckv | kr16-rope | pad)
    gemm16d<0><<<dim3(17, BT/128), blk, 0, stream>>>(x16, cqT, Dm,
        cq, ckv, kr16, nullptr, nullptr, cstab);
    kropebc_kernel<<<dim3(256), blk, 0, stream>>>(kr16, out_k);

    rmsnorm2_kernel<<<dim3(BT, 2), blk, 0, stream>>>(cq, g_q, ckv, g_kv);

    // fused Q GEMM: N=3072 (qn | qr-rope)  [reads cstab; must precede KV GEMM]
    gemm16d<1><<<dim3(24, BT/128), blk, 0, stream>>>(cq, dqnT, QRc,
        qn, qr, nullptr, nullptr, nullptr, cstab);
    // fused KV GEMM: N=4096 (kn+out_k | vt+out_v)  [overwrites cstab & weight region]
    gemm16d<2><<<dim3(32, BT/128), blk, 0, stream>>>(ckv, dknT, KVRc,
        kn, nullptr, vt, out_k, out_v, nullptr);

    // attention (swapped-QK 32x32, in-register softmax)
    attn8_kernel<<<dim3(512), blk, 0, stream>>>(qn, qr, kn, kr16, vt, ao);

    // output projection
    gemm16d<3><<<dim3(16, BT/128), blk, 0, stream>>>(ao, outT, Dm,
        nullptr, nullptr, nullptr, out_o, nullptr, nullptr);
}

// Round 9
// 383.785 us; speedup vs baseline: 1.2687x; 1.2687x over previous
//
#include <hip/hip_runtime.h>
#include <cstdint>
#include <cstddef>

typedef _Float16 HT;
typedef _Float16 h8 __attribute__((ext_vector_type(8)));
typedef _Float16 h4 __attribute__((ext_vector_type(4)));
typedef float f32x4 __attribute__((ext_vector_type(4)));

constexpr int Tn  = 2048;
constexpr int Dm  = 2048;
constexpr int Hh  = 16;
constexpr int RDc = 64;
constexpr int QRc = 1536;
constexpr int KVRc= 512;
constexpr int BT  = 4096;

#define VWAIT(N) asm volatile("s_waitcnt vmcnt(" #N ")" ::: "memory")
#define SBAR()   __builtin_amdgcn_s_barrier()

__device__ __forceinline__ f32x4 mfma16(h8 a, h8 b, f32x4 c) {
    return __builtin_amdgcn_mfma_f32_16x16x32_f16(a, b, c, 0, 0, 0);
}
__device__ __forceinline__ void gload_lds16(const void* g, void* l) {
    __builtin_amdgcn_global_load_lds(
        (const __attribute__((address_space(1))) unsigned int*)g,
        (__attribute__((address_space(3))) unsigned int*)l, 16, 0, 0);
}

// ---------------------------------------------------------------------------
__global__ __launch_bounds__(256)
void cstab_kernel(float2* __restrict__ cs)
{
    const int idx = blockIdx.x * 256 + threadIdx.x;   // 65536
    const int t = idx >> 5, i = idx & 31;
    const float ang = (float)t * exp2f(-(float)i * (13.287712379549449f / 32.f));
    cs[idx] = make_float2(cosf(ang), sinf(ang));
}

// ---------------------------------------------------------------------------
struct WT8 {
    const float* s[8];
    HT* d[8];
    int K[8], N[8], start[8];
};

__global__ __launch_bounds__(256)
void wtrans8_kernel(WT8 p)
{
    __shared__ float Ts[64][65];
    int seg = 0;
    #pragma unroll
    for (int i = 1; i < 8; i++) if ((int)blockIdx.x >= p.start[i]) seg = i;
    const float* src = p.s[seg];
    HT* dst = p.d[seg];
    const int K = p.K[seg], N = p.N[seg];
    const int bx = blockIdx.x - p.start[seg];
    const int nx = N >> 6;
    const int n0 = (bx % nx) * 64, k0 = (bx / nx) * 64;
    const int tid = threadIdx.x;
    {
        const int r = tid >> 2, c0 = (tid & 3) * 16;
        const float* s = src + (size_t)(k0 + r) * N + n0 + c0;
        #pragma unroll
        for (int j = 0; j < 4; j++)
            *reinterpret_cast<f32x4*>(&Ts[r][c0 + j * 4]) = *reinterpret_cast<const f32x4*>(s + j * 4);
    }
    __syncthreads();
    {
        const int c = tid >> 2, kq = (tid & 3) * 16;
        h8 o0, o1;
        #pragma unroll
        for (int j = 0; j < 8; j++) { o0[j] = (HT)Ts[kq + j][c]; o1[j] = (HT)Ts[kq + 8 + j][c]; }
        HT* d = dst + (size_t)(n0 + c) * K + k0 + kq;
        *reinterpret_cast<h8*>(d)     = o0;
        *reinterpret_cast<h8*>(d + 8) = o1;
    }
}

// ---------------------------------------------------------------------------
__global__ __launch_bounds__(256)
void convx_kernel(const float* __restrict__ x, HT* __restrict__ x16)
{
    const size_t i = ((size_t)blockIdx.x * 256 + threadIdx.x) * 8;
    f32x4 a = *reinterpret_cast<const f32x4*>(x + i);
    f32x4 b = *reinterpret_cast<const f32x4*>(x + i + 4);
    h8 v;
    #pragma unroll
    for (int j = 0; j < 4; j++) { v[j] = (HT)a[j]; v[4 + j] = (HT)b[j]; }
    *reinterpret_cast<h8*>(x16 + i) = v;
}

// ---------------------------------------------------------------------------
// 8-phase ring GEMM (T3+T4): BM=256, BN=128, BK=64 (two k-32 halves),
// 512 threads = 8 waves (4M x 2N, wave C = 64x64). LDS = 4 half-slot ring,
// slot = A-half 16KB + B-half 8KB = 24KB -> 96KB dynamic. Per half-step:
// ds_read 8 frags | issue 3 gload_lds (slot 3 ahead) | vmcnt(6) | barrier |
// lgkmcnt(0) | 16 MFMA | barrier. vmcnt never drains to 0 in the loop.
// A fp16 [M][K], Bt fp16 [N][K]. EPI: 0=latent 1=Q 2=KV 3=OUT.
// ---------------------------------------------------------------------------
template<int EPI>
__global__ __launch_bounds__(512, 2)
void gemm8p(const HT* __restrict__ A, const HT* __restrict__ Bt, const int K,
            HT* __restrict__ o1, HT* __restrict__ o2, HT* __restrict__ o3,
            float* __restrict__ f1, float* __restrict__ f2,
            const float2* __restrict__ cstab)
{
    extern __shared__ char smem[];          // 4 slots x 24576 B

    const int tid  = threadIdx.x;
    const int lane = tid & 63;
    const int l15  = lane & 15, l4 = lane >> 4;
    const int w    = tid >> 6;              // 0..7
    const int wr   = w >> 1, wc = w & 1;    // 4M x 2N
    const int m0   = blockIdx.y * 256;
    const int n0   = blockIdx.x * 128;

    f32x4 acc[4][4] = {};
    const int nk = K >> 6;                  // 64-wide K tiles

    // swizzles (involution): staged chunk / read chunk
    const int sch = (lane & 3) ^ ((lane >> 2) & 3) ^ ((lane >> 4) & 3);
    const int swr = (l15 & 3) ^ ((l15 >> 2) & 3);

    // staging row bases (per thread)
    const int sarow = w * 32 + (lane >> 2);   // A rows (+0 / +16)
    const int sbrow = w * 16 + (lane >> 2);   // B rows

#define STAGE(slot_, srck_) do {                                               \
    HT* stg_ = (HT*)(smem + (slot_) * 24576);                                  \
    gload_lds16(A  + (size_t)(m0 + sarow)      * K + (srck_) + sch * 8,        \
                stg_ + w * 1024);                                              \
    gload_lds16(A  + (size_t)(m0 + sarow + 16) * K + (srck_) + sch * 8,        \
                stg_ + w * 1024 + 512);                                        \
    gload_lds16(Bt + (size_t)(n0 + sbrow)      * K + (srck_) + sch * 8,        \
                stg_ + 8192 + w * 512);                                        \
    } while (0)

#define PHASE(cons_, stg_, srck_) do {                                         \
    const char* sa_ = smem + (cons_) * 24576;                                  \
    h8 af_[4], bf_[4];                                                         \
    _Pragma("unroll")                                                          \
    for (int i_ = 0; i_ < 4; i_++)                                             \
        af_[i_] = *(const h8*)(sa_ + (wr * 64 + i_ * 16 + l15) * 64            \
                                   + (l4 ^ swr) * 16);                         \
    _Pragma("unroll")                                                          \
    for (int j_ = 0; j_ < 4; j_++)                                             \
        bf_[j_] = *(const h8*)(sa_ + 16384 + (wc * 64 + j_ * 16 + l15) * 64    \
                                   + (l4 ^ swr) * 16);                         \
    STAGE(stg_, srck_);                                                        \
    VWAIT(6);                                                                  \
    SBAR();                                                                    \
    asm volatile("s_waitcnt lgkmcnt(0)" ::: "memory");                         \
    __builtin_amdgcn_sched_barrier(0);                                         \
    __builtin_amdgcn_s_setprio(1);                                             \
    _Pragma("unroll")                                                          \
    for (int i_ = 0; i_ < 4; i_++)                                             \
        _Pragma("unroll")                                                      \
        for (int j_ = 0; j_ < 4; j_++)                                         \
            acc[i_][j_] = mfma16(af_[i_], bf_[j_], acc[i_][j_]);               \
    __builtin_amdgcn_s_setprio(0);                                             \
    SBAR();                                                                    \
    } while (0)

    // prologue: slots 0,1,2 <- (t0,k0), (t0,k32), (t1,k0)
    STAGE(0, 0);
    STAGE(1, 32);
    STAGE(2, 64);
    VWAIT(6);
    SBAR();

    for (int t = 0; t < nk; t++) {
        const int s0 = (2 * t) & 3;
        const int s1 = (2 * t + 1) & 3;
        const int st0 = (2 * t + 3) & 3;
        const int k1 = (t + 1 < nk ? t + 1 : nk - 1) * 64 + 32;  // (t+1, ks1)
        const int k2 = (t + 2 < nk ? t + 2 : nk - 1) * 64;       // (t+2, ks0)
        PHASE(s0, st0, k1);
        PHASE(s1, s0,  k2);
    }
    VWAIT(0);
#undef PHASE
#undef STAGE

    #pragma unroll
    for (int i = 0; i < 4; i++) {
        #pragma unroll
        for (int j = 0; j < 4; j++) {
            const int row = m0 + wr * 64 + i * 16 + l4 * 4;
            const int col = n0 + wc * 64 + j * 16 + l15;
            if constexpr (EPI == 3) {
                #pragma unroll
                for (int r = 0; r < 4; r++)
                    f1[(size_t)(row + r) * 2048 + col] = acc[i][j][r];
            } else if constexpr (EPI == 0) {
                if (col < 1536) {
                    #pragma unroll
                    for (int r = 0; r < 4; r++)
                        o1[(size_t)(row + r) * 1536 + col] = (HT)acc[i][j][r];
                } else if (col < 2048) {
                    #pragma unroll
                    for (int r = 0; r < 4; r++)
                        o2[(size_t)(row + r) * 512 + (col - 1536)] = (HT)acc[i][j][r];
                } else if (col < 2112) {
                    const int cc = col - 2048;
                    const int ii = cc >> 1;
                    const bool odd = cc & 1;
                    #pragma unroll
                    for (int r = 0; r < 4; r++) {
                        const int t = (row + r) & (Tn - 1);
                        const float2 cs = cstab[t * 32 + ii];
                        const float v = acc[i][j][r];
                        const float p = __shfl_xor(v, 1);
                        const float ov = odd ? p * cs.y + v * cs.x : v * cs.x - p * cs.y;
                        o3[(size_t)(row + r) * 64 + cc] = (HT)ov;
                    }
                }
            } else if constexpr (EPI == 1) {
                if (col < 2048) {
                    #pragma unroll
                    for (int r = 0; r < 4; r++)
                        o1[(size_t)(row + r) * 2048 + col] = (HT)acc[i][j][r];
                } else {
                    const int cc = col - 2048;
                    const int ii = (cc & 63) >> 1;
                    const bool odd = cc & 1;
                    #pragma unroll
                    for (int r = 0; r < 4; r++) {
                        const int t = (row + r) & (Tn - 1);
                        const float2 cs = cstab[t * 32 + ii];
                        const float v = acc[i][j][r];
                        const float p = __shfl_xor(v, 1);
                        const float ov = odd ? p * cs.y + v * cs.x : v * cs.x - p * cs.y;
                        o2[(size_t)(row + r) * 1024 + cc] = (HT)ov;
                    }
                }
            } else {  // EPI == 2
                if (col < 2048) {
                    const int h = col >> 7, d = col & 127;
                    #pragma unroll
                    for (int r = 0; r < 4; r++) {
                        const int rw = row + r;
                        const int b = rw >> 11, t = rw & (Tn - 1);
                        o1[(size_t)rw * 2048 + col] = (HT)acc[i][j][r];
                        f1[((size_t)(b * Hh + h) * Tn + t) * 192 + d] = acc[i][j][r];
                    }
                } else {
                    const int c2 = col - 2048;
                    const int h = c2 >> 7, d = c2 & 127;
                    const int b = row >> 11, t0 = row & (Tn - 1);
                    h4 pk;
                    #pragma unroll
                    for (int r = 0; r < 4; r++) {
                        f2[((size_t)(b * Hh + h) * Tn + t0 + r) * 128 + d] = acc[i][j][r];
                        pk[r] = (HT)acc[i][j][r];
                    }
                    *reinterpret_cast<h4*>(&o3[((size_t)(b * Hh + h) * 128 + d) * Tn + t0]) = pk;
                }
            }
        }
    }
}

// ---------------------------------------------------------------------------
__global__ __launch_bounds__(256)
void kropebc_kernel(const HT* __restrict__ kr16, float* __restrict__ out_k)
{
    const int idx = blockIdx.x * 256 + threadIdx.x;    // 2*2048*16
    const int j4 = (idx & 15) * 4;
    const int t  = (idx >> 4) & (Tn - 1);
    const int b  = idx >> 15;
    h4 v = *reinterpret_cast<const h4*>(&kr16[((size_t)(b * Tn + t)) * 64 + j4]);
    f32x4 f;
    #pragma unroll
    for (int r = 0; r < 4; r++) f[r] = (float)v[r];
    #pragma unroll
    for (int h = 0; h < Hh; h++)
        *reinterpret_cast<f32x4*>(&out_k[((size_t)(b * Hh + h) * Tn + t) * 192 + 128 + j4]) = f;
}

// ---------------------------------------------------------------------------
__global__ __launch_bounds__(256)
void rmsnorm2_kernel(HT* __restrict__ Xa, const float* __restrict__ ga,
                     HT* __restrict__ Xb, const float* __restrict__ gb)
{
    const int which = blockIdx.y;
    HT* X = which ? Xb : Xa;
    const float* g = which ? gb : ga;
    const int N = which ? 512 : 1536;
    const int row = blockIdx.x;
    HT* x = X + (size_t)row * N;
    float ss = 0.f;
    for (int i = threadIdx.x * 8; i < N; i += 2048) {
        h8 v = *reinterpret_cast<const h8*>(&x[i]);
        #pragma unroll
        for (int j = 0; j < 8; j++) { float f = (float)v[j]; ss += f * f; }
    }
    #pragma unroll
    for (int sh = 32; sh >= 1; sh >>= 1) ss += __shfl_xor(ss, sh);
    __shared__ float red[4];
    if ((threadIdx.x & 63) == 0) red[threadIdx.x >> 6] = ss;
    __syncthreads();
    const float tot = red[0] + red[1] + red[2] + red[3];
    const float scale = rsqrtf(tot / (float)N + 1e-6f);
    for (int i = threadIdx.x * 8; i < N; i += 2048) {
        h8 v = *reinterpret_cast<const h8*>(&x[i]);
        f32x4 g0 = *reinterpret_cast<const f32x4*>(&g[i]);
        f32x4 g1 = *reinterpret_cast<const f32x4*>(&g[i + 4]);
        #pragma unroll
        for (int j = 0; j < 4; j++) { v[j]   = (HT)((float)v[j]   * scale * g0[j]);
                                      v[4+j] = (HT)((float)v[4+j] * scale * g1[j]); }
        *reinterpret_cast<h8*>(&x[i]) = v;
    }
}

// ---------------------------------------------------------------------------
// Flash attention v7 (proven 136us): QBLK=32 per wave via mirrored q-tiles.
// ---------------------------------------------------------------------------
__global__ __launch_bounds__(256, 2)
void attn7_kernel(const HT* __restrict__ qn, const HT* __restrict__ qr,
                  const HT* __restrict__ kn, const HT* __restrict__ kr16,
                  const HT* __restrict__ vt, HT* __restrict__ ao)
{
    __shared__ HT Ks_n[64 * 128];
    __shared__ HT Vs[128 * 64];
    __shared__ HT Ps[4][32][72];

    const int tid  = threadIdx.x;
    const int lane = tid & 63;
    const int l15  = lane & 15, l4 = lane >> 4;
    const int w    = tid >> 6;

    const int bid = blockIdx.x;          // 512
    const int j   = bid >> 5;
    const int h   = bid & 15;
    const int b   = (bid >> 4) & 1;
    const int thi = 31 - j;

    const size_t bT = (size_t)b * Tn;
    const HT* vt_h = vt + ((size_t)(b * Hh + h) * 128) * Tn;
    const HT* krb  = kr16 + bT * 64;

    const int qw0 = j   * 64 + w * 16;
    const int qw1 = thi * 64 + w * 16;

    h8 aq0[6], aq1[6];
    {
        const size_t rq0 = bT + qw0 + l15;
        const HT* pn = qn + rq0 * 2048 + h * 128 + l4 * 8;
        #pragma unroll
        for (int f = 0; f < 4; f++) aq0[f] = *reinterpret_cast<const h8*>(pn + f * 32);
        const HT* pr = qr + rq0 * 1024 + h * 64 + l4 * 8;
        aq0[4] = *reinterpret_cast<const h8*>(pr);
        aq0[5] = *reinterpret_cast<const h8*>(pr + 32);
        const size_t rq1 = bT + qw1 + l15;
        const HT* pn1 = qn + rq1 * 2048 + h * 128 + l4 * 8;
        #pragma unroll
        for (int f = 0; f < 4; f++) aq1[f] = *reinterpret_cast<const h8*>(pn1 + f * 32);
        const HT* pr1 = qr + rq1 * 1024 + h * 64 + l4 * 8;
        aq1[4] = *reinterpret_cast<const h8*>(pr1);
        aq1[5] = *reinterpret_cast<const h8*>(pr1 + 32);
    }

    f32x4 o0[8] = {}, o1[8] = {};
    float m0v[4] = {-1e30f, -1e30f, -1e30f, -1e30f};
    float m1v[4] = {-1e30f, -1e30f, -1e30f, -1e30f};
    float l0v[4] = {0.f, 0.f, 0.f, 0.f};
    float l1v[4] = {0.f, 0.f, 0.f, 0.f};

    const float scl = 0.07216878364870323f;  // 1/sqrt(192)

#define SOFTMAX(sv, mv, lv, ov, qwx, prow)                                      \
{                                                                               \
    float al_[4];                                                               \
    _Pragma("unroll")                                                           \
    for (int r = 0; r < 4; r++) {                                               \
        const int qrow = (qwx) + l4 * 4 + r;                                    \
        float a_[4];                                                            \
        _Pragma("unroll")                                                       \
        for (int c = 0; c < 4; c++)                                             \
            a_[c] = (kb + c * 16 + l15 <= qrow) ? sv[c][r] * scl : -1e30f;      \
        float mx = fmaxf(fmaxf(a_[0], a_[1]), fmaxf(a_[2], a_[3]));             \
        _Pragma("unroll")                                                       \
        for (int sh = 1; sh < 16; sh <<= 1) mx = fmaxf(mx, __shfl_xor(mx, sh)); \
        const float mn = fmaxf(mv[r], mx);                                      \
        const float alpha = __expf(mv[r] - mn);                                 \
        mv[r] = mn;                                                             \
        float rs = 0.f;                                                         \
        _Pragma("unroll")                                                       \
        for (int c = 0; c < 4; c++) {                                           \
            const float e = __expf(a_[c] - mn);                                 \
            rs += e;                                                            \
            Ps[w][(prow) + l4 * 4 + r][c * 16 + l15] = (HT)e;                   \
        }                                                                       \
        _Pragma("unroll")                                                       \
        for (int sh = 1; sh < 16; sh <<= 1) rs += __shfl_xor(rs, sh);           \
        lv[r] = lv[r] * alpha + rs;                                             \
        al_[r] = alpha;                                                         \
    }                                                                           \
    _Pragma("unroll")                                                           \
    for (int g = 0; g < 8; g++)                                                 \
        _Pragma("unroll")                                                       \
        for (int r = 0; r < 4; r++) ov[g][r] *= al_[r];                         \
}

#define KBODY(ACT0)                                                             \
{                                                                               \
    f32x4 s0[4] = {}, s1[4] = {};                                               \
    __builtin_amdgcn_s_setprio(1);                                              \
    _Pragma("unroll")                                                           \
    for (int c = 0; c < 4; c++) {                                               \
        const int kr = c * 16 + l15;                                            \
        const HT* rp = krb + (size_t)(kb + kr) * 64 + l4 * 8;                   \
        const h8 br0 = *reinterpret_cast<const h8*>(rp);                        \
        const h8 br1 = *reinterpret_cast<const h8*>(rp + 32);                   \
        const int sw = (kr & 7) << 4;                                           \
        const char* kbase = (const char*)Ks_n + kr * 256;                       \
        _Pragma("unroll")                                                       \
        for (int f = 0; f < 4; f++) {                                           \
            const h8 kf = *(const h8*)(kbase + ((f * 64 + l4 * 16) ^ sw));      \
            s1[c] = mfma16(aq1[f], kf, s1[c]);                                  \
            if (ACT0) s0[c] = mfma16(aq0[f], kf, s0[c]);                        \
        }                                                                       \
        s1[c] = mfma16(aq1[4], br0, s1[c]);                                     \
        s1[c] = mfma16(aq1[5], br1, s1[c]);                                     \
        if (ACT0) { s0[c] = mfma16(aq0[4], br0, s0[c]);                         \
                    s0[c] = mfma16(aq0[5], br1, s0[c]); }                       \
    }                                                                           \
    __builtin_amdgcn_s_setprio(0);                                              \
    SOFTMAX(s1, m1v, l1v, o1, qw1, 16);                                         \
    if (ACT0) SOFTMAX(s0, m0v, l0v, o0, qw0, 0);                                \
    const h8 ap10 = *reinterpret_cast<const h8*>(&Ps[w][16 + l15][l4 * 8]);     \
    const h8 ap11 = *reinterpret_cast<const h8*>(&Ps[w][16 + l15][32 + l4 * 8]);\
    h8 ap00 = ap10, ap01 = ap11;                                                \
    if (ACT0) {                                                                 \
        ap00 = *reinterpret_cast<const h8*>(&Ps[w][l15][l4 * 8]);               \
        ap01 = *reinterpret_cast<const h8*>(&Ps[w][l15][32 + l4 * 8]);          \
    }                                                                           \
    __builtin_amdgcn_s_setprio(1);                                              \
    _Pragma("unroll")                                                           \
    for (int g = 0; g < 8; g++) {                                               \
        const int d = g * 16 + l15;                                             \
        const int sw = (d & 7) << 4;                                            \
        const char* vbase = (const char*)Vs + d * 128;                          \
        const h8 v0 = *(const h8*)(vbase + ((l4 * 16) ^ sw));                   \
        const h8 v1 = *(const h8*)(vbase + ((64 + l4 * 16) ^ sw));              \
        o1[g] = mfma16(ap10, v0, o1[g]);                                        \
        o1[g] = mfma16(ap11, v1, o1[g]);                                        \
        if (ACT0) { o0[g] = mfma16(ap00, v0, o0[g]);                            \
                    o0[g] = mfma16(ap01, v1, o0[g]); }                          \
    }                                                                           \
    __builtin_amdgcn_s_setprio(0);                                              \
}

    const int nkb = thi + 1;
    for (int kb64 = 0; kb64 < nkb; kb64++) {
        const int kb = kb64 * 64;
        __syncthreads();
        #pragma unroll
        for (int jj = 0; jj < 4; jj++) {
            const int r = (w * 4 + jj) * 4 + l4;
            const int cl = (l15 & 8) | ((l15 & 7) ^ (r & 7));
            gload_lds16(kn + (bT + kb + r) * 2048 + h * 128 + cl * 8,
                        &Ks_n[(w * 4 + jj) * 512]);
        }
        #pragma unroll
        for (int jj = 0; jj < 4; jj++) {
            const int d = (w * 4 + jj) * 8 + (lane >> 3);
            const int cl = (lane & 7) ^ (d & 7);
            gload_lds16(vt_h + (size_t)d * Tn + kb + cl * 8,
                        &Vs[(w * 4 + jj) * 512]);
        }
        __syncthreads();

        if (kb <= qw0 + 15) KBODY(1) else KBODY(0)
    }
#undef KBODY
#undef SOFTMAX

    {
        const size_t orow = bT + qw1 + l4 * 4;
        #pragma unroll
        for (int r = 0; r < 4; r++) {
            const float inv = 1.0f / l1v[r];
            HT* dst = ao + (orow + r) * 2048 + h * 128 + l15;
            #pragma unroll
            for (int g = 0; g < 8; g++) dst[g * 16] = (HT)(o1[g][r] * inv);
        }
    }
    {
        const size_t orow = bT + qw0 + l4 * 4;
        #pragma unroll
        for (int r = 0; r < 4; r++) {
            const float inv = 1.0f / l0v[r];
            HT* dst = ao + (orow + r) * 2048 + h * 128 + l15;
            #pragma unroll
            for (int g = 0; g < 8; g++) dst[g * 16] = (HT)(o0[g][r] * inv);
        }
    }
}

// ---------------------------------------------------------------------------
extern "C" void kernel_launch(void* const* d_in, const int* in_sizes, int n_in,
                              void* d_out, int out_size, void* d_ws, size_t ws_size,
                              hipStream_t stream)
{
    const float* x     = (const float*)d_in[0];
    const float* w_cq  = (const float*)d_in[1];
    const float* g_q   = (const float*)d_in[2];
    const float* w_ckv = (const float*)d_in[3];
    const float* g_kv  = (const float*)d_in[4];
    const float* w_dqn = (const float*)d_in[5];
    const float* w_dqr = (const float*)d_in[6];
    const float* w_dkn = (const float*)d_in[7];
    const float* w_dv  = (const float*)d_in[8];
    const float* w_kr  = (const float*)d_in[9];
    const float* w_out = (const float*)d_in[10];

    char* ws = (char*)d_ws;
    HT* cqT   = (HT*)(ws + 0);           // [1536][2048]  6,291,456
    HT* ckvT  = (HT*)(ws + 6291456);     // [512][2048]   2,097,152
    HT* krT   = (HT*)(ws + 8388608);     // [64][2048]      262,144
    //  pad region [8650752, 8912896) read as garbage B rows (never written out)
    HT* dqnT  = (HT*)(ws + 8912896);     // [2048][1536]  6,291,456
    HT* dqrT  = (HT*)(ws + 15204352);    // [1024][1536]  3,145,728
    HT* dknT  = (HT*)(ws + 18350080);    // [2048][512]   2,097,152
    HT* dvT   = (HT*)(ws + 20447232);    // [2048][512]   2,097,152
    HT* outT  = (HT*)(ws + 22544384);    // [2048][2048]  8,388,608
    HT* cq    = (HT*)(ws + 30932992);    // [4096][1536] 12,582,912
    HT* ckv   = (HT*)(ws + 43515904);    // [4096][512]   4,194,304
    HT* qn    = (HT*)(ws + 47710208);    // [4096][2048] 16,777,216 (x16/ao alias)
    HT* qr    = (HT*)(ws + 64487424);    // [4096][1024]  8,388,608
    HT* kn    = (HT*)(ws + 72876032);    // [4096][2048] 16,777,216
    HT* kr16  = (HT*)(ws + 89653248);    // [4096][64]      524,288
    HT* vt    = (HT*)(ws + 0);           // [2][16][128][2048] 16,777,216 (alias)
    HT* x16   = qn;
    HT* ao    = qn;

    float* out_o = (float*)d_out;
    float* out_k = out_o + (size_t)BT * Dm;
    float* out_v = out_k + (size_t)2 * Hh * Tn * 192;
    float2* cstab = (float2*)out_v;      // stashed; overwritten after Q GEMM

    const dim3 blk(256);
    const unsigned GEMM_LDS = 98304;

    // allow 96KB dynamic LDS (ignore errors; HIP typically allows directly)
    (void)hipFuncSetAttribute((const void*)gemm8p<0>, hipFuncAttributeMaxDynamicSharedMemorySize, (int)GEMM_LDS);
    (void)hipFuncSetAttribute((const void*)gemm8p<1>, hipFuncAttributeMaxDynamicSharedMemorySize, (int)GEMM_LDS);
    (void)hipFuncSetAttribute((const void*)gemm8p<2>, hipFuncAttributeMaxDynamicSharedMemorySize, (int)GEMM_LDS);
    (void)hipFuncSetAttribute((const void*)gemm8p<3>, hipFuncAttributeMaxDynamicSharedMemorySize, (int)GEMM_LDS);

    cstab_kernel<<<dim3(256), blk, 0, stream>>>(cstab);

    WT8 wt;
    wt.s[0]=w_cq;  wt.d[0]=cqT;  wt.K[0]=2048; wt.N[0]=1536;
    wt.s[1]=w_ckv; wt.d[1]=ckvT; wt.K[1]=2048; wt.N[1]=512;
    wt.s[2]=w_kr;  wt.d[2]=krT;  wt.K[2]=2048; wt.N[2]=64;
    wt.s[3]=w_dqn; wt.d[3]=dqnT; wt.K[3]=1536; wt.N[3]=2048;
    wt.s[4]=w_dqr; wt.d[4]=dqrT; wt.K[4]=1536; wt.N[4]=1024;
    wt.s[5]=w_dkn; wt.d[5]=dknT; wt.K[5]=512;  wt.N[5]=2048;
    wt.s[6]=w_dv;  wt.d[6]=dvT;  wt.K[6]=512;  wt.N[6]=2048;
    wt.s[7]=w_out; wt.d[7]=outT; wt.K[7]=2048; wt.N[7]=2048;
    {
        int acc = 0;
        for (int i = 0; i < 8; i++) {
            wt.start[i] = acc;
            acc += (wt.N[i] >> 6) * (wt.K[i] >> 6);
        }
        wtrans8_kernel<<<dim3(acc), blk, 0, stream>>>(wt);
    }

    convx_kernel<<<dim3(4096), blk, 0, stream>>>(x, x16);

    // fused latent GEMM: N=2176 (cq | ckv | kr16-rope | pad)
    gemm8p<0><<<dim3(17, 16), dim3(512), GEMM_LDS, stream>>>(x16, cqT, Dm,
        cq, ckv, kr16, nullptr, nullptr, cstab);
    kropebc_kernel<<<dim3(256), blk, 0, stream>>>(kr16, out_k);

    rmsnorm2_kernel<<<dim3(BT, 2), blk, 0, stream>>>(cq, g_q, ckv, g_kv);

    // fused Q GEMM: N=3072 (qn | qr-rope)  [reads cstab; must precede KV GEMM]
    gemm8p<1><<<dim3(24, 16), dim3(512), GEMM_LDS, stream>>>(cq, dqnT, QRc,
        qn, qr, nullptr, nullptr, nullptr, cstab);
    // fused KV GEMM: N=4096 (kn+out_k | vt+out_v)  [overwrites cstab & weights]
    gemm8p<2><<<dim3(32, 16), dim3(512), GEMM_LDS, stream>>>(ckv, dknT, KVRc,
        kn, nullptr, vt, out_k, out_v, nullptr);

    // attention (proven attn7)
    attn7_kernel<<<dim3(512), blk, 0, stream>>>(qn, qr, kn, kr16, vt, ao);

    // output projection
    gemm8p<3><<<dim3(16, 16), dim3(512), GEMM_LDS, stream>>>(ao, outT, Dm,
        nullptr, nullptr, nullptr, out_o, nullptr, nullptr);
}